// Round 2
// baseline (589.692 us; speedup 1.0000x reference)
//
#include <hip/hip_runtime.h>
#include <stdint.h>

// Problem: B=8, S=1024, NX=1024, H=16, D=64 (GPT-2 attention block)
// out = [ a: B*S*NX ][ present_k: B*H*S*D ][ present_v: B*H*S*D ]
// Input/output dtype sniffed at runtime (fp32 vs bf16); internals bf16.

#define BB 8
#define SS 1024
#define NXX 1024
#define NH 16
#define HD 64

typedef __bf16 bf16x8 __attribute__((ext_vector_type(8)));
typedef float  floatx4 __attribute__((ext_vector_type(4)));
typedef unsigned short ushort8 __attribute__((ext_vector_type(8)));

__device__ inline float bf2f(unsigned short u) {
    unsigned int x = ((unsigned int)u) << 16;
    float f;
    __builtin_memcpy(&f, &x, 4);
    return f;
}
__device__ inline unsigned short f2bf(float f) {
    unsigned int u;
    __builtin_memcpy(&u, &f, 4);
    u += 0x7FFFu + ((u >> 16) & 1u);  // RNE
    return (unsigned short)(u >> 16);
}

// ---------------- dtype sniff: flag=1 if data is fp32, 0 if bf16 ----------------
__global__ void sniff_k(const unsigned short* __restrict__ x, int* __restrict__ flag) {
    if (threadIdx.x == 0 && blockIdx.x == 0) {
        int g = 0;
        for (int i = 0; i < 512; i++) {
            float f = bf2f(x[i]);
            float a = fabsf(f);
            // garbage if NaN/inf/huge, or denormal-tiny nonzero
            if (!(a <= 1e4f)) g++;
            else if (f != 0.f && a < 1e-35f) g++;
        }
        *flag = (g > 16) ? 1 : 0;
    }
}

// ---------------- transpose+convert: out_bf16[C][R] = in[R][C] ----------------
__global__ __launch_bounds__(256) void transpose_k(
    const void* __restrict__ in, unsigned short* __restrict__ out,
    int R, int C, const int* __restrict__ flagp) {
    const int f32 = *flagp;
    __shared__ unsigned short tile[32][33];
    int c0 = blockIdx.x * 32, r0 = blockIdx.y * 32;
    int tx = threadIdx.x & 31, ty = threadIdx.x >> 5;  // 32 x 8
    if (f32) {
        const float* inf = (const float*)in;
#pragma unroll
        for (int i = ty; i < 32; i += 8)
            tile[i][tx] = f2bf(inf[(r0 + i) * C + c0 + tx]);
    } else {
        const unsigned short* inu = (const unsigned short*)in;
#pragma unroll
        for (int i = ty; i < 32; i += 8)
            tile[i][tx] = inu[(r0 + i) * C + c0 + tx];
    }
    __syncthreads();
#pragma unroll
    for (int i = ty; i < 32; i += 8)
        out[(c0 + i) * R + r0 + tx] = tile[tx][i];
}

// ---------------- GEMM: C[M,N] = A[M,K] @ Bt[N,K]^T + bias[N] ----------------
// MODE 0: A is internal bf16 (amerged); writes out0 (=d_out `a`) in flag dtype.
// MODE 1: A is external (flag dtype, =x); QKV scatter: q -> q_ws (bf16),
//         k/v -> d_out regions (flag dtype), [B,H,S,D] layout.
template <int MODE>
__global__ __launch_bounds__(256) void gemm_bt(
    const void* __restrict__ A,
    const unsigned short* __restrict__ Bt,
    const void* __restrict__ bias,
    void* __restrict__ outbase,          // d_out base
    unsigned short* __restrict__ q_ws,   // MODE 1 only
    int M, int N, int K, const int* __restrict__ flagp) {
    __shared__ __align__(16) unsigned short As[128 * 32];
    __shared__ __align__(16) unsigned short Bs[128 * 32];

    const int f32 = *flagp;
    const int tid  = threadIdx.x;
    const int lane = tid & 63;
    const int wave = tid >> 6;
    const int wr = wave >> 1, wc = wave & 1;
    const int l15 = lane & 15;
    const int quad = lane >> 4;
    const int row0 = blockIdx.y * 128;
    const int col0 = blockIdx.x * 128;

    floatx4 acc[4][4];
    floatx4 zz = {0.f, 0.f, 0.f, 0.f};
#pragma unroll
    for (int i = 0; i < 4; i++)
#pragma unroll
        for (int j = 0; j < 4; j++) acc[i][j] = zz;

    const int srow = tid >> 1;         // 0..127
    const int skel = (tid & 1) * 16;   // 0 or 16
    const int a_is_f32 = (MODE == 1) ? f32 : 0;

    for (int k0 = 0; k0 < K; k0 += 32) {
        if (a_is_f32) {
            const float* Af = (const float*)A;
            const floatx4* p = (const floatx4*)&Af[(size_t)(row0 + srow) * K + k0 + skel];
            floatx4 f0 = p[0], f1 = p[1], f2 = p[2], f3 = p[3];
            ushort8 u0, u1;
#pragma unroll
            for (int j = 0; j < 4; j++) { u0[j] = f2bf(f0[j]); u0[4 + j] = f2bf(f1[j]); }
#pragma unroll
            for (int j = 0; j < 4; j++) { u1[j] = f2bf(f2[j]); u1[4 + j] = f2bf(f3[j]); }
            *(ushort8*)&As[srow * 32 + skel]     = u0;
            *(ushort8*)&As[srow * 32 + skel + 8] = u1;
        } else {
            const unsigned short* Au = (const unsigned short*)A;
            *(ushort8*)&As[srow * 32 + skel]     = *(const ushort8*)&Au[(size_t)(row0 + srow) * K + k0 + skel];
            *(ushort8*)&As[srow * 32 + skel + 8] = *(const ushort8*)&Au[(size_t)(row0 + srow) * K + k0 + skel + 8];
        }
        *(ushort8*)&Bs[srow * 32 + skel]     = *(const ushort8*)&Bt[(size_t)(col0 + srow) * K + k0 + skel];
        *(ushort8*)&Bs[srow * 32 + skel + 8] = *(const ushort8*)&Bt[(size_t)(col0 + srow) * K + k0 + skel + 8];
        __syncthreads();

        bf16x8 af[4], bfr[4];
#pragma unroll
        for (int mi = 0; mi < 4; mi++)
            af[mi] = *(const bf16x8*)&As[(wr * 64 + mi * 16 + l15) * 32 + quad * 8];
#pragma unroll
        for (int ni = 0; ni < 4; ni++)
            bfr[ni] = *(const bf16x8*)&Bs[(wc * 64 + ni * 16 + l15) * 32 + quad * 8];
#pragma unroll
        for (int mi = 0; mi < 4; mi++)
#pragma unroll
            for (int ni = 0; ni < 4; ni++)
                acc[mi][ni] = __builtin_amdgcn_mfma_f32_16x16x32_bf16(af[mi], bfr[ni], acc[mi][ni], 0, 0, 0);
        __syncthreads();
    }

    const size_t esz = f32 ? 4 : 2;
    char* kbase = (char*)outbase + (size_t)(BB * SS * NXX) * esz;
    char* vbase = (char*)outbase + (size_t)(2 * BB * SS * NXX) * esz;

#pragma unroll
    for (int mi = 0; mi < 4; mi++) {
#pragma unroll
        for (int ni = 0; ni < 4; ni++) {
            const int colb = col0 + wc * 64 + ni * 16 + l15;
            const float bv = f32 ? ((const float*)bias)[colb] : bf2f(((const unsigned short*)bias)[colb]);
#pragma unroll
            for (int i = 0; i < 4; i++) {
                const int row = row0 + wr * 64 + mi * 16 + quad * 4 + i;
                const float val = acc[mi][ni][i] + bv;
                if (MODE == 0) {
                    const size_t idx = (size_t)row * N + colb;
                    if (f32) ((float*)outbase)[idx] = val;
                    else     ((unsigned short*)outbase)[idx] = f2bf(val);
                } else {
                    const int sec    = colb >> 10;
                    const int within = colb & 1023;
                    const int h = within >> 6;
                    const int d = within & 63;
                    const int b = row >> 10;
                    const int s = row & 1023;
                    const size_t idx = (size_t)((b * NH + h) * SS + s) * HD + d;
                    if (sec == 0) {
                        q_ws[idx] = f2bf(val);
                    } else {
                        char* base = (sec == 1) ? kbase : vbase;
                        if (f32) ((float*)base)[idx] = val;
                        else     ((unsigned short*)base)[idx] = f2bf(val);
                    }
                }
            }
        }
    }
}

// ---------------- flash attention, 1 wave per 16-row Q tile ----------------
// q_ws: [B,H,S,D] bf16. K/V read from d_out (flag dtype). amerged: [B,S,NX] bf16.
__global__ __launch_bounds__(64) void attn(
    const unsigned short* __restrict__ q_ws,
    const void* __restrict__ outbase,
    unsigned short* __restrict__ amerged,
    const int* __restrict__ flagp) {
    const int f32 = *flagp;
    const int lane = threadIdx.x;
    const int l15 = lane & 15, quad = lane >> 4;
    const int blk = blockIdx.x;       // ((b*NH+h)*64 + qt)
    const int qt = blk & 63;
    const int bh = blk >> 6;
    const int b = bh >> 4, h = bh & 15;
    const int qbase = qt * 16;

    const size_t esz = f32 ? 4 : 2;
    const char* kraw = (const char*)outbase + (size_t)(BB * SS * NXX) * esz + (size_t)bh * (SS * HD) * esz;
    const char* vraw = (const char*)outbase + (size_t)(2 * BB * SS * NXX) * esz + (size_t)bh * (SS * HD) * esz;
    const unsigned short* Q = q_ws + (size_t)bh * (SS * HD);

    __shared__ __align__(16) unsigned short Pl[16 * 32];

    bf16x8 qa[2];
#pragma unroll
    for (int t = 0; t < 2; t++)
        qa[t] = *(const bf16x8*)&Q[(qbase + l15) * HD + t * 32 + quad * 8];

    floatx4 zz = {0.f, 0.f, 0.f, 0.f};
    floatx4 o[4];
#pragma unroll
    for (int nf = 0; nf < 4; nf++) o[nf] = zz;
    float mrow[4], lrow[4];
#pragma unroll
    for (int i = 0; i < 4; i++) { mrow[i] = -1e30f; lrow[i] = 0.f; }

    const int qmax = qbase + 15;
    for (int j0 = 0; j0 <= qmax; j0 += 32) {
        // ---- scores: S[16 q][32 key] via two 16x16x32 MFMAs per 16-key half
        floatx4 sf[2];
#pragma unroll
        for (int c = 0; c < 2; c++) {
            const int key = j0 + c * 16 + l15;
            bf16x8 kb0, kb1;
            if (f32) {
                const float* Kf = (const float*)kraw + (size_t)key * HD;
                ushort8 t0, t1;
#pragma unroll
                for (int j = 0; j < 8; j++) { t0[j] = f2bf(Kf[quad * 8 + j]); t1[j] = f2bf(Kf[32 + quad * 8 + j]); }
                kb0 = __builtin_bit_cast(bf16x8, t0);
                kb1 = __builtin_bit_cast(bf16x8, t1);
            } else {
                const unsigned short* Ku = (const unsigned short*)kraw + (size_t)key * HD;
                kb0 = *(const bf16x8*)&Ku[quad * 8];
                kb1 = *(const bf16x8*)&Ku[32 + quad * 8];
            }
            floatx4 s = zz;
            s = __builtin_amdgcn_mfma_f32_16x16x32_bf16(qa[0], kb0, s, 0, 0, 0);
            s = __builtin_amdgcn_mfma_f32_16x16x32_bf16(qa[1], kb1, s, 0, 0, 0);
            sf[c] = s;
        }

        // ---- scale + causal mask + online softmax (row = quad*4+i, key lane = l15)
        float pv[2][4], alpha[4];
#pragma unroll
        for (int i = 0; i < 4; i++) {
            const int qrow = qbase + quad * 4 + i;
#pragma unroll
            for (int c = 0; c < 2; c++) {
                const int key = j0 + c * 16 + l15;
                float s = sf[c][i] * 0.125f;
                if (key > qrow) s = -10000.0f;  // matches reference mask value
                pv[c][i] = s;
            }
            float t = fmaxf(pv[0][i], pv[1][i]);
            t = fmaxf(t, __shfl_xor(t, 1));
            t = fmaxf(t, __shfl_xor(t, 2));
            t = fmaxf(t, __shfl_xor(t, 4));
            t = fmaxf(t, __shfl_xor(t, 8));
            const float mnew = fmaxf(mrow[i], t);
            alpha[i] = __expf(mrow[i] - mnew);
            mrow[i] = mnew;
            float rs = 0.f;
#pragma unroll
            for (int c = 0; c < 2; c++) {
                const float p = __expf(pv[c][i] - mnew);
                pv[c][i] = p;
                rs += p;
            }
            rs += __shfl_xor(rs, 1);
            rs += __shfl_xor(rs, 2);
            rs += __shfl_xor(rs, 4);
            rs += __shfl_xor(rs, 8);
            lrow[i] = lrow[i] * alpha[i] + rs;
        }

        // ---- P: C-layout -> A-layout via LDS round trip
        __syncthreads();
#pragma unroll
        for (int i = 0; i < 4; i++)
#pragma unroll
            for (int c = 0; c < 2; c++)
                Pl[(quad * 4 + i) * 32 + c * 16 + l15] = f2bf(pv[c][i]);
        __syncthreads();
        bf16x8 pa = *(const bf16x8*)&Pl[l15 * 32 + quad * 8];

        // ---- O = O*alpha + P @ V[32 keys, 64 d]
#pragma unroll
        for (int nf = 0; nf < 4; nf++) {
#pragma unroll
            for (int i = 0; i < 4; i++) o[nf][i] *= alpha[i];
            ushort8 vv;
            if (f32) {
                const float* Vf = (const float*)vraw;
#pragma unroll
                for (int j = 0; j < 8; j++)
                    vv[j] = f2bf(Vf[(size_t)(j0 + quad * 8 + j) * HD + nf * 16 + l15]);
            } else {
                const unsigned short* Vu = (const unsigned short*)vraw;
#pragma unroll
                for (int j = 0; j < 8; j++)
                    vv[j] = Vu[(size_t)(j0 + quad * 8 + j) * HD + nf * 16 + l15];
            }
            o[nf] = __builtin_amdgcn_mfma_f32_16x16x32_bf16(pa, __builtin_bit_cast(bf16x8, vv), o[nf], 0, 0, 0);
        }
        __syncthreads();  // protect Pl before next iteration overwrites
    }

#pragma unroll
    for (int nf = 0; nf < 4; nf++)
#pragma unroll
        for (int i = 0; i < 4; i++) {
            const int s = qbase + quad * 4 + i;
            amerged[(size_t)(b * SS + s) * NXX + h * HD + nf * 16 + l15] = f2bf(o[nf][i] / lrow[i]);
        }
}

extern "C" void kernel_launch(void* const* d_in, const int* in_sizes, int n_in,
                              void* d_out, int out_size, void* d_ws, size_t ws_size,
                              hipStream_t stream) {
    const void* x     = d_in[0];
    const void* Wqkv  = d_in[1];
    const void* bqkv  = d_in[2];
    const void* Wproj = d_in[3];
    const void* bproj = d_in[4];

    int* flag = (int*)d_ws;
    unsigned short* ws = (unsigned short*)d_ws + 8;     // 16B in
    unsigned short* WqkvT   = ws;                       // 3072*1024
    unsigned short* WprojT  = WqkvT + 3072 * 1024;      // 1024*1024
    unsigned short* q_ws    = WprojT + 1024 * 1024;     // B*H*S*D = 8M
    unsigned short* amerged = q_ws + 8 * 1024 * 1024;   // B*S*NX = 8M
    // total ws: ~42 MB

    sniff_k<<<1, 64, 0, stream>>>((const unsigned short*)x, flag);
    transpose_k<<<dim3(3072 / 32, 1024 / 32), 256, 0, stream>>>(Wqkv, WqkvT, 1024, 3072, flag);
    transpose_k<<<dim3(1024 / 32, 1024 / 32), 256, 0, stream>>>(Wproj, WprojT, 1024, 1024, flag);
    gemm_bt<1><<<dim3(3072 / 128, 8192 / 128), 256, 0, stream>>>(
        x, WqkvT, bqkv, d_out, q_ws, 8192, 3072, 1024, flag);
    attn<<<dim3(BB * NH * (SS / 16)), 64, 0, stream>>>(q_ws, d_out, amerged, flag);
    gemm_bt<0><<<dim3(1024 / 128, 8192 / 128), 256, 0, stream>>>(
        amerged, WprojT, bproj, d_out, nullptr, 8192, 1024, 1024, flag);
}

// Round 3
// 477.035 us; speedup vs baseline: 1.2362x; 1.2362x over previous
//
#include <hip/hip_runtime.h>
#include <stdint.h>

// Problem: B=8, S=1024, NX=1024, H=16, D=64 (GPT-2 attention block)
// out = [ a: B*S*NX ][ present_k: B*H*S*D ][ present_v: B*H*S*D ]
// Input/output dtype sniffed at runtime (fp32 vs bf16); internals bf16.

#define BB 8
#define SS 1024
#define NXX 1024
#define NH 16
#define HD 64

typedef __bf16 bf16x8 __attribute__((ext_vector_type(8)));
typedef float  floatx4 __attribute__((ext_vector_type(4)));
typedef unsigned short ushort8 __attribute__((ext_vector_type(8)));

__device__ inline float bf2f(unsigned short u) {
    unsigned int x = ((unsigned int)u) << 16;
    float f;
    __builtin_memcpy(&f, &x, 4);
    return f;
}
__device__ inline unsigned short f2bf(float f) {
    unsigned int u;
    __builtin_memcpy(&u, &f, 4);
    u += 0x7FFFu + ((u >> 16) & 1u);  // RNE
    return (unsigned short)(u >> 16);
}

// ---------------- dtype sniff: flag=1 if data is fp32, 0 if bf16 ----------------
__global__ void sniff_k(const unsigned short* __restrict__ x, int* __restrict__ flag) {
    if (threadIdx.x == 0 && blockIdx.x == 0) {
        int g = 0;
        for (int i = 0; i < 512; i++) {
            float f = bf2f(x[i]);
            float a = fabsf(f);
            if (!(a <= 1e4f)) g++;
            else if (f != 0.f && a < 1e-35f) g++;
        }
        *flag = (g > 16) ? 1 : 0;
    }
}

// ---------------- transpose+convert: out_bf16[C][R] = in[R][C] ----------------
__global__ __launch_bounds__(256) void transpose_k(
    const void* __restrict__ in, unsigned short* __restrict__ out,
    int R, int C, const int* __restrict__ flagp) {
    const int f32 = *flagp;
    __shared__ unsigned short tile[32][33];
    int c0 = blockIdx.x * 32, r0 = blockIdx.y * 32;
    int tx = threadIdx.x & 31, ty = threadIdx.x >> 5;  // 32 x 8
    if (f32) {
        const float* inf = (const float*)in;
#pragma unroll
        for (int i = ty; i < 32; i += 8)
            tile[i][tx] = f2bf(inf[(r0 + i) * C + c0 + tx]);
    } else {
        const unsigned short* inu = (const unsigned short*)in;
#pragma unroll
        for (int i = ty; i < 32; i += 8)
            tile[i][tx] = inu[(r0 + i) * C + c0 + tx];
    }
    __syncthreads();
#pragma unroll
    for (int i = ty; i < 32; i += 8)
        out[(c0 + i) * R + r0 + tx] = tile[tx][i];
}

// ---------------- GEMM: C[M,N] = A[M,K] @ Bt[N,K]^T + bias[N] ----------------
// MODE 0: A internal bf16 (amerged); writes `a` region of d_out in flag dtype.
// MODE 1: A external (flag dtype, =x); QKV scatter:
//   q -> q_ws (bf16 [bh][s][d]); k -> d_out + kbf (bf16 [bh][s][d]);
//   v -> d_out + vbfT (bf16 [bh][d][s]).
template <int MODE>
__global__ __launch_bounds__(256) void gemm_bt(
    const void* __restrict__ A,
    const unsigned short* __restrict__ Bt,
    const void* __restrict__ bias,
    void* __restrict__ outbase,          // d_out base
    unsigned short* __restrict__ q_ws,   // MODE 1
    unsigned short* __restrict__ kbf,    // MODE 1
    unsigned short* __restrict__ vbfT,   // MODE 1
    int M, int N, int K, const int* __restrict__ flagp) {
    __shared__ __align__(16) unsigned short As[128 * 32];
    __shared__ __align__(16) unsigned short Bs[128 * 32];

    const int f32 = *flagp;
    const int tid  = threadIdx.x;
    const int lane = tid & 63;
    const int wave = tid >> 6;
    const int wr = wave >> 1, wc = wave & 1;
    const int l15 = lane & 15;
    const int quad = lane >> 4;
    const int row0 = blockIdx.y * 128;
    const int col0 = blockIdx.x * 128;

    floatx4 acc[4][4];
    floatx4 zz = {0.f, 0.f, 0.f, 0.f};
#pragma unroll
    for (int i = 0; i < 4; i++)
#pragma unroll
        for (int j = 0; j < 4; j++) acc[i][j] = zz;

    const int srow = tid >> 1;         // 0..127
    const int skel = (tid & 1) * 16;   // 0 or 16
    const int a_is_f32 = (MODE == 1) ? f32 : 0;

    for (int k0 = 0; k0 < K; k0 += 32) {
        if (a_is_f32) {
            const float* Af = (const float*)A;
            const floatx4* p = (const floatx4*)&Af[(size_t)(row0 + srow) * K + k0 + skel];
            floatx4 f0 = p[0], f1 = p[1], f2 = p[2], f3 = p[3];
            ushort8 u0, u1;
#pragma unroll
            for (int j = 0; j < 4; j++) { u0[j] = f2bf(f0[j]); u0[4 + j] = f2bf(f1[j]); }
#pragma unroll
            for (int j = 0; j < 4; j++) { u1[j] = f2bf(f2[j]); u1[4 + j] = f2bf(f3[j]); }
            *(ushort8*)&As[srow * 32 + skel]     = u0;
            *(ushort8*)&As[srow * 32 + skel + 8] = u1;
        } else {
            const unsigned short* Au = (const unsigned short*)A;
            *(ushort8*)&As[srow * 32 + skel]     = *(const ushort8*)&Au[(size_t)(row0 + srow) * K + k0 + skel];
            *(ushort8*)&As[srow * 32 + skel + 8] = *(const ushort8*)&Au[(size_t)(row0 + srow) * K + k0 + skel + 8];
        }
        *(ushort8*)&Bs[srow * 32 + skel]     = *(const ushort8*)&Bt[(size_t)(col0 + srow) * K + k0 + skel];
        *(ushort8*)&Bs[srow * 32 + skel + 8] = *(const ushort8*)&Bt[(size_t)(col0 + srow) * K + k0 + skel + 8];
        __syncthreads();

        bf16x8 af[4], bfr[4];
#pragma unroll
        for (int mi = 0; mi < 4; mi++)
            af[mi] = *(const bf16x8*)&As[(wr * 64 + mi * 16 + l15) * 32 + quad * 8];
#pragma unroll
        for (int ni = 0; ni < 4; ni++)
            bfr[ni] = *(const bf16x8*)&Bs[(wc * 64 + ni * 16 + l15) * 32 + quad * 8];
#pragma unroll
        for (int mi = 0; mi < 4; mi++)
#pragma unroll
            for (int ni = 0; ni < 4; ni++)
                acc[mi][ni] = __builtin_amdgcn_mfma_f32_16x16x32_bf16(af[mi], bfr[ni], acc[mi][ni], 0, 0, 0);
        __syncthreads();
    }

    const size_t esz = f32 ? 4 : 2;
    char* kbase = (char*)outbase + (size_t)(BB * SS * NXX) * esz;
    char* vbase = (char*)outbase + (size_t)(2 * BB * SS * NXX) * esz;

#pragma unroll
    for (int mi = 0; mi < 4; mi++) {
#pragma unroll
        for (int ni = 0; ni < 4; ni++) {
            const int colb = col0 + wc * 64 + ni * 16 + l15;
            const float bv = f32 ? ((const float*)bias)[colb] : bf2f(((const unsigned short*)bias)[colb]);
#pragma unroll
            for (int i = 0; i < 4; i++) {
                const int row = row0 + wr * 64 + mi * 16 + quad * 4 + i;
                const float val = acc[mi][ni][i] + bv;
                if (MODE == 0) {
                    const size_t idx = (size_t)row * N + colb;
                    if (f32) ((float*)outbase)[idx] = val;
                    else     ((unsigned short*)outbase)[idx] = f2bf(val);
                } else {
                    const int sec    = colb >> 10;
                    const int within = colb & 1023;
                    const int h = within >> 6;
                    const int d = within & 63;
                    const int b = row >> 10;
                    const int s = row & 1023;
                    const int bh = b * NH + h;
                    const size_t idx = (size_t)(bh * SS + s) * HD + d;
                    const unsigned short obf = f2bf(val);
                    if (sec == 0) {
                        q_ws[idx] = obf;
                    } else if (sec == 1) {
                        if (f32) ((float*)kbase)[idx] = val;
                        else     ((unsigned short*)kbase)[idx] = obf;
                        kbf[idx] = obf;
                    } else {
                        if (f32) ((float*)vbase)[idx] = val;
                        else     ((unsigned short*)vbase)[idx] = obf;
                        vbfT[(size_t)(bh * HD + d) * SS + s] = obf;
                    }
                }
            }
        }
    }
}

// ---------------- flash attention: 4 waves/block, 128 Q rows, 64-key tiles --------
// q_ws/kbf: [bh][s][d] bf16; vbfT: [bh][d][s] bf16; amerged: [B,S,NX] bf16.
__global__ __launch_bounds__(256) void attn(
    const unsigned short* __restrict__ q_ws,
    const unsigned short* __restrict__ kbf,
    const unsigned short* __restrict__ vbfT,
    unsigned short* __restrict__ amerged) {
    const int tid = threadIdx.x;
    const int lane = tid & 63;
    const int w = tid >> 6;              // wave 0..3
    const int l15 = lane & 15, quad = lane >> 4;
    const int blk = blockIdx.x;
    const int qb = blk & 7;              // q-block 0..7 (128 rows each)
    const int bh = blk >> 3;
    const int b = bh >> 4, h = bh & 15;
    const int qbase = qb * 128;
    const int wrow0 = qbase + w * 32;    // wave's first Q row

    const unsigned short* Q = q_ws + (size_t)bh * (SS * HD);
    const unsigned short* K = kbf + (size_t)bh * (SS * HD);
    const unsigned short* V = vbfT + (size_t)bh * (HD * SS);

    __shared__ __align__(16) unsigned short Ks[64][72];     // [key][d], pad
    __shared__ __align__(16) unsigned short Vs[64][72];     // [d][key], pad
    __shared__ __align__(16) unsigned short Pl[4][32][72];  // per-wave P, pad

    // Q A-frags: qa[m][t]  (m: 16-row frag, t: K-half of D=64)
    bf16x8 qa[2][2];
#pragma unroll
    for (int m = 0; m < 2; m++)
#pragma unroll
        for (int t = 0; t < 2; t++)
            qa[m][t] = *(const bf16x8*)&Q[(size_t)(wrow0 + m * 16 + l15) * HD + t * 32 + quad * 8];

    floatx4 zz = {0.f, 0.f, 0.f, 0.f};
    floatx4 o[2][4];
    float mrow[2][4], lrow[2][4];
#pragma unroll
    for (int m = 0; m < 2; m++)
#pragma unroll
        for (int i = 0; i < 4; i++) { mrow[m][i] = -1e30f; lrow[m][i] = 0.f; }
#pragma unroll
    for (int m = 0; m < 2; m++)
#pragma unroll
        for (int nf = 0; nf < 4; nf++) o[m][nf] = zz;

    const int wq_max = wrow0 + 31;
    const int jend = qbase + 128;

    // staging indices
    const int srow = tid >> 2;          // 0..63
    const int soff = (tid & 3) * 16;

    for (int j0 = 0; j0 < jend; j0 += 64) {
        // ---- cooperative K/V staging (bf16, vectorized) ----
        *(ushort8*)&Ks[srow][soff]     = *(const ushort8*)&K[(size_t)(j0 + srow) * HD + soff];
        *(ushort8*)&Ks[srow][soff + 8] = *(const ushort8*)&K[(size_t)(j0 + srow) * HD + soff + 8];
        *(ushort8*)&Vs[srow][soff]     = *(const ushort8*)&V[(size_t)srow * SS + j0 + soff];
        *(ushort8*)&Vs[srow][soff + 8] = *(const ushort8*)&V[(size_t)srow * SS + j0 + soff + 8];
        __syncthreads();

        if (j0 <= wq_max) {
            // ---- scores: sf[m][kg] over 64 keys ----
            floatx4 sf[2][4];
#pragma unroll
            for (int kg = 0; kg < 4; kg++) {
                bf16x8 kb0 = *(const bf16x8*)&Ks[kg * 16 + l15][quad * 8];
                bf16x8 kb1 = *(const bf16x8*)&Ks[kg * 16 + l15][32 + quad * 8];
#pragma unroll
                for (int m = 0; m < 2; m++) {
                    floatx4 s = zz;
                    s = __builtin_amdgcn_mfma_f32_16x16x32_bf16(qa[m][0], kb0, s, 0, 0, 0);
                    s = __builtin_amdgcn_mfma_f32_16x16x32_bf16(qa[m][1], kb1, s, 0, 0, 0);
                    sf[m][kg] = s;
                }
            }

            // ---- online softmax (row = wrow0 + m*16 + quad*4 + i; key lane = l15) ----
            float alpha_[2][4];
#pragma unroll
            for (int m = 0; m < 2; m++)
#pragma unroll
                for (int i = 0; i < 4; i++) {
                    const int qrow = wrow0 + m * 16 + quad * 4 + i;
                    float pv4[4];
#pragma unroll
                    for (int kg = 0; kg < 4; kg++) {
                        const int key = j0 + kg * 16 + l15;
                        float s = sf[m][kg][i] * 0.125f;
                        if (key > qrow) s = -10000.0f;
                        pv4[kg] = s;
                    }
                    float t = fmaxf(fmaxf(pv4[0], pv4[1]), fmaxf(pv4[2], pv4[3]));
                    t = fmaxf(t, __shfl_xor(t, 1));
                    t = fmaxf(t, __shfl_xor(t, 2));
                    t = fmaxf(t, __shfl_xor(t, 4));
                    t = fmaxf(t, __shfl_xor(t, 8));
                    const float mnew = fmaxf(mrow[m][i], t);
                    const float al = __expf(mrow[m][i] - mnew);
                    mrow[m][i] = mnew;
                    float rs = 0.f;
#pragma unroll
                    for (int kg = 0; kg < 4; kg++) {
                        const float p = __expf(pv4[kg] - mnew);
                        Pl[w][m * 16 + quad * 4 + i][kg * 16 + l15] = f2bf(p);
                        rs += p;
                    }
                    rs += __shfl_xor(rs, 1);
                    rs += __shfl_xor(rs, 2);
                    rs += __shfl_xor(rs, 4);
                    rs += __shfl_xor(rs, 8);
                    lrow[m][i] = lrow[m][i] * al + rs;
                    alpha_[m][i] = al;
                }

            // ---- O rescale ----
#pragma unroll
            for (int m = 0; m < 2; m++)
#pragma unroll
                for (int nf = 0; nf < 4; nf++)
#pragma unroll
                    for (int i = 0; i < 4; i++) o[m][nf][i] *= alpha_[m][i];

            // ---- P A-frags (wave-internal LDS round trip) ----
            bf16x8 pa[2][2];
#pragma unroll
            for (int m = 0; m < 2; m++) {
                pa[m][0] = *(const bf16x8*)&Pl[w][m * 16 + l15][quad * 8];
                pa[m][1] = *(const bf16x8*)&Pl[w][m * 16 + l15][32 + quad * 8];
            }

            // ---- PV ----
#pragma unroll
            for (int nf = 0; nf < 4; nf++) {
                bf16x8 vb0 = *(const bf16x8*)&Vs[nf * 16 + l15][quad * 8];
                bf16x8 vb1 = *(const bf16x8*)&Vs[nf * 16 + l15][32 + quad * 8];
#pragma unroll
                for (int m = 0; m < 2; m++) {
                    o[m][nf] = __builtin_amdgcn_mfma_f32_16x16x32_bf16(pa[m][0], vb0, o[m][nf], 0, 0, 0);
                    o[m][nf] = __builtin_amdgcn_mfma_f32_16x16x32_bf16(pa[m][1], vb1, o[m][nf], 0, 0, 0);
                }
            }
        }
        __syncthreads();
    }

    // ---- epilogue ----
#pragma unroll
    for (int m = 0; m < 2; m++)
#pragma unroll
        for (int nf = 0; nf < 4; nf++)
#pragma unroll
            for (int i = 0; i < 4; i++) {
                const int s = wrow0 + m * 16 + quad * 4 + i;
                amerged[(size_t)(b * SS + s) * NXX + h * HD + nf * 16 + l15] =
                    f2bf(o[m][nf][i] / lrow[m][i]);
            }
}

extern "C" void kernel_launch(void* const* d_in, const int* in_sizes, int n_in,
                              void* d_out, int out_size, void* d_ws, size_t ws_size,
                              hipStream_t stream) {
    const void* x     = d_in[0];
    const void* Wqkv  = d_in[1];
    const void* bqkv  = d_in[2];
    const void* Wproj = d_in[3];
    const void* bproj = d_in[4];

    int* flag = (int*)d_ws;
    unsigned short* ws = (unsigned short*)d_ws + 8;
    unsigned short* WqkvT   = ws;                        // 3072*1024      (6 MB)
    unsigned short* WprojT  = WqkvT + 3072 * 1024;       // 1024*1024      (2 MB)
    unsigned short* q_ws    = WprojT + 1024 * 1024;      // 8M             (16 MB)
    unsigned short* kbf     = q_ws + 8 * 1024 * 1024;    // 8M             (16 MB)
    unsigned short* vbfT    = kbf + 8 * 1024 * 1024;     // 8M             (16 MB)
    unsigned short* amerged = vbfT + 8 * 1024 * 1024;    // 8M             (16 MB)
    // total ws: ~72 MB

    sniff_k<<<1, 64, 0, stream>>>((const unsigned short*)x, flag);
    transpose_k<<<dim3(3072 / 32, 1024 / 32), 256, 0, stream>>>(Wqkv, WqkvT, 1024, 3072, flag);
    transpose_k<<<dim3(1024 / 32, 1024 / 32), 256, 0, stream>>>(Wproj, WprojT, 1024, 1024, flag);
    gemm_bt<1><<<dim3(3072 / 128, 8192 / 128), 256, 0, stream>>>(
        x, WqkvT, bqkv, d_out, q_ws, kbf, vbfT, 8192, 3072, 1024, flag);
    attn<<<dim3(BB * NH * (SS / 128)), 256, 0, stream>>>(q_ws, kbf, vbfT, amerged);
    gemm_bt<0><<<dim3(1024 / 128, 8192 / 128), 256, 0, stream>>>(
        amerged, WprojT, bproj, d_out, nullptr, nullptr, nullptr, 8192, 1024, 1024, flag);
}

// Round 4
// 454.481 us; speedup vs baseline: 1.2975x; 1.0496x over previous
//
#include <hip/hip_runtime.h>
#include <stdint.h>

// Problem: B=8, S=1024, NX=1024, H=16, D=64 (GPT-2 attention block)
// out = [ a: B*S*NX ][ present_k: B*H*S*D ][ present_v: B*H*S*D ]
// Input/output dtype sniffed at runtime (fp32 vs bf16); internals bf16.

#define BB 8
#define SS 1024
#define NXX 1024
#define NH 16
#define HD 64

typedef __bf16 bf16x8 __attribute__((ext_vector_type(8)));
typedef float  floatx4 __attribute__((ext_vector_type(4)));
typedef unsigned short ushort8 __attribute__((ext_vector_type(8)));

__device__ inline float bf2f(unsigned short u) {
    unsigned int x = ((unsigned int)u) << 16;
    float f;
    __builtin_memcpy(&f, &x, 4);
    return f;
}
__device__ inline unsigned short f2bf(float f) {
    unsigned int u;
    __builtin_memcpy(&u, &f, 4);
    u += 0x7FFFu + ((u >> 16) & 1u);  // RNE
    return (unsigned short)(u >> 16);
}

// async global->LDS, 16B per lane (dest = wave-uniform base + lane*16)
__device__ inline void gload_lds16(const unsigned short* g, unsigned short* l) {
    __builtin_amdgcn_global_load_lds(
        (const __attribute__((address_space(1))) void*)g,
        (__attribute__((address_space(3))) void*)l, 16, 0, 0);
}

// ---------------- dtype sniff: flag=1 if data is fp32, 0 if bf16 ----------------
__global__ void sniff_k(const unsigned short* __restrict__ x, int* __restrict__ flag) {
    if (threadIdx.x == 0 && blockIdx.x == 0) {
        int g = 0;
        for (int i = 0; i < 512; i++) {
            float f = bf2f(x[i]);
            float a = fabsf(f);
            if (!(a <= 1e4f)) g++;
            else if (f != 0.f && a < 1e-35f) g++;
        }
        *flag = (g > 16) ? 1 : 0;
    }
}

// ---------------- convert x -> bf16 (8 elems/thread) ----------------
__global__ __launch_bounds__(256) void convert_x(
    const void* __restrict__ in, unsigned short* __restrict__ out,
    const int* __restrict__ flagp) {
    const int f32 = *flagp;
    const size_t i = ((size_t)blockIdx.x * 256 + threadIdx.x) * 8;
    if (f32) {
        const floatx4* p = (const floatx4*)((const float*)in + i);
        floatx4 f0 = p[0], f1 = p[1];
        ushort8 u;
#pragma unroll
        for (int j = 0; j < 4; j++) { u[j] = f2bf(f0[j]); u[4 + j] = f2bf(f1[j]); }
        *(ushort8*)(out + i) = u;
    } else {
        *(ushort8*)(out + i) = *(const ushort8*)((const unsigned short*)in + i);
    }
}

// ---------------- transpose+convert: out_bf16[C][R] = in[R][C] ----------------
__global__ __launch_bounds__(256) void transpose_k(
    const void* __restrict__ in, unsigned short* __restrict__ out,
    int R, int C, const int* __restrict__ flagp) {
    const int f32 = *flagp;
    __shared__ unsigned short tile[32][33];
    int c0 = blockIdx.x * 32, r0 = blockIdx.y * 32;
    int tx = threadIdx.x & 31, ty = threadIdx.x >> 5;  // 32 x 8
    if (f32) {
        const float* inf = (const float*)in;
#pragma unroll
        for (int i = ty; i < 32; i += 8)
            tile[i][tx] = f2bf(inf[(r0 + i) * C + c0 + tx]);
    } else {
        const unsigned short* inu = (const unsigned short*)in;
#pragma unroll
        for (int i = ty; i < 32; i += 8)
            tile[i][tx] = inu[(r0 + i) * C + c0 + tx];
    }
    __syncthreads();
#pragma unroll
    for (int i = ty; i < 32; i += 8)
        out[(c0 + i) * R + r0 + tx] = tile[tx][i];
}

// ---------------- GEMM: C[M,N] = A[M,K] @ Bt[N,K]^T + bias[N] ----------------
// A, Bt: bf16. Staging via global_load_lds (16B/lane, m97 structure).
// MODE 0: writes `a` region of d_out in flag dtype.
// MODE 1: QKV scatter: q -> q_ws (bf16 [bh][s][d]); k -> d_out + kbf (bf16);
//         v -> d_out + vbfT (bf16 [bh][d][s]).
template <int MODE>
__global__ __launch_bounds__(256) void gemm_bt(
    const unsigned short* __restrict__ A,
    const unsigned short* __restrict__ Bt,
    const void* __restrict__ bias,
    void* __restrict__ outbase,
    unsigned short* __restrict__ q_ws,
    unsigned short* __restrict__ kbf,
    unsigned short* __restrict__ vbfT,
    int M, int N, int K, const int* __restrict__ flagp) {
    __shared__ __align__(16) unsigned short As[128 * 32];
    __shared__ __align__(16) unsigned short Bs[128 * 32];

    const int f32 = *flagp;
    const int tid  = threadIdx.x;
    const int lane = tid & 63;
    const int wave = tid >> 6;
    const int wr = wave >> 1, wc = wave & 1;
    const int l15 = lane & 15;
    const int quad = lane >> 4;
    const int row0 = blockIdx.y * 128;
    const int col0 = blockIdx.x * 128;

    floatx4 acc[4][4];
    floatx4 zz = {0.f, 0.f, 0.f, 0.f};
#pragma unroll
    for (int i = 0; i < 4; i++)
#pragma unroll
        for (int j = 0; j < 4; j++) acc[i][j] = zz;

    // DMA staging geometry: per wave, 2 instrs per buffer; each instr covers
    // 16 rows x 32 cols (64 lanes x 16B). lane -> row = lane>>2, col = (lane&3)*8.
    const int lrow = lane >> 2;
    const int lcol = (lane & 3) * 8;
    const unsigned short* Ag = A  + (size_t)(row0 + wave * 32 + lrow) * K + lcol;
    const unsigned short* Bg = Bt + (size_t)(col0 + wave * 32 + lrow) * K + lcol;
    unsigned short* Asl0 = &As[(wave * 32) * 32];
    unsigned short* Asl1 = &As[(wave * 32 + 16) * 32];
    unsigned short* Bsl0 = &Bs[(wave * 32) * 32];
    unsigned short* Bsl1 = &Bs[(wave * 32 + 16) * 32];

    for (int k0 = 0; k0 < K; k0 += 32) {
        gload_lds16(Ag + k0, Asl0);
        gload_lds16(Ag + k0 + (size_t)16 * K, Asl1);
        gload_lds16(Bg + k0, Bsl0);
        gload_lds16(Bg + k0 + (size_t)16 * K, Bsl1);
        __syncthreads();

        bf16x8 af[4], bfr[4];
#pragma unroll
        for (int mi = 0; mi < 4; mi++)
            af[mi] = *(const bf16x8*)&As[(wr * 64 + mi * 16 + l15) * 32 + quad * 8];
#pragma unroll
        for (int ni = 0; ni < 4; ni++)
            bfr[ni] = *(const bf16x8*)&Bs[(wc * 64 + ni * 16 + l15) * 32 + quad * 8];
#pragma unroll
        for (int mi = 0; mi < 4; mi++)
#pragma unroll
            for (int ni = 0; ni < 4; ni++)
                acc[mi][ni] = __builtin_amdgcn_mfma_f32_16x16x32_bf16(af[mi], bfr[ni], acc[mi][ni], 0, 0, 0);
        __syncthreads();
    }

    const size_t esz = f32 ? 4 : 2;
    char* kbase = (char*)outbase + (size_t)(BB * SS * NXX) * esz;
    char* vbase = (char*)outbase + (size_t)(2 * BB * SS * NXX) * esz;

#pragma unroll
    for (int mi = 0; mi < 4; mi++) {
#pragma unroll
        for (int ni = 0; ni < 4; ni++) {
            const int colb = col0 + wc * 64 + ni * 16 + l15;
            const float bv = f32 ? ((const float*)bias)[colb] : bf2f(((const unsigned short*)bias)[colb]);
#pragma unroll
            for (int i = 0; i < 4; i++) {
                const int row = row0 + wr * 64 + mi * 16 + quad * 4 + i;
                const float val = acc[mi][ni][i] + bv;
                if (MODE == 0) {
                    const size_t idx = (size_t)row * N + colb;
                    if (f32) ((float*)outbase)[idx] = val;
                    else     ((unsigned short*)outbase)[idx] = f2bf(val);
                } else {
                    const int sec    = colb >> 10;
                    const int within = colb & 1023;
                    const int h = within >> 6;
                    const int d = within & 63;
                    const int b = row >> 10;
                    const int s = row & 1023;
                    const int bh = b * NH + h;
                    const size_t idx = (size_t)(bh * SS + s) * HD + d;
                    const unsigned short obf = f2bf(val);
                    if (sec == 0) {
                        q_ws[idx] = obf;
                    } else if (sec == 1) {
                        if (f32) ((float*)kbase)[idx] = val;
                        else     ((unsigned short*)kbase)[idx] = obf;
                        kbf[idx] = obf;
                    } else {
                        if (f32) ((float*)vbase)[idx] = val;
                        else     ((unsigned short*)vbase)[idx] = obf;
                        vbfT[(size_t)(bh * HD + d) * SS + s] = obf;
                    }
                }
            }
        }
    }
}

// ---------------- flash attention: 4 waves/block, 128 Q rows, 64-key tiles --------
// q_ws/kbf: [bh][s][d] bf16; vbfT: [bh][d][s] bf16; amerged: [B,S,NX] bf16.
__global__ __launch_bounds__(256) void attn(
    const unsigned short* __restrict__ q_ws,
    const unsigned short* __restrict__ kbf,
    const unsigned short* __restrict__ vbfT,
    unsigned short* __restrict__ amerged) {
    const int tid = threadIdx.x;
    const int lane = tid & 63;
    const int w = tid >> 6;
    const int l15 = lane & 15, quad = lane >> 4;
    const int blk = blockIdx.x;
    const int qb = blk & 7;
    const int bh = blk >> 3;
    const int b = bh >> 4, h = bh & 15;
    const int qbase = qb * 128;
    const int wrow0 = qbase + w * 32;

    const unsigned short* Q = q_ws + (size_t)bh * (SS * HD);
    const unsigned short* K = kbf + (size_t)bh * (SS * HD);
    const unsigned short* V = vbfT + (size_t)bh * (HD * SS);

    __shared__ __align__(16) unsigned short Ks[64][72];
    __shared__ __align__(16) unsigned short Vs[64][72];
    __shared__ __align__(16) unsigned short Pl[4][32][72];

    bf16x8 qa[2][2];
#pragma unroll
    for (int m = 0; m < 2; m++)
#pragma unroll
        for (int t = 0; t < 2; t++)
            qa[m][t] = *(const bf16x8*)&Q[(size_t)(wrow0 + m * 16 + l15) * HD + t * 32 + quad * 8];

    floatx4 zz = {0.f, 0.f, 0.f, 0.f};
    floatx4 o[2][4];
    float mrow[2][4], lrow[2][4];
#pragma unroll
    for (int m = 0; m < 2; m++)
#pragma unroll
        for (int i = 0; i < 4; i++) { mrow[m][i] = -1e30f; lrow[m][i] = 0.f; }
#pragma unroll
    for (int m = 0; m < 2; m++)
#pragma unroll
        for (int nf = 0; nf < 4; nf++) o[m][nf] = zz;

    const int wq_max = wrow0 + 31;
    const int jend = qbase + 128;

    const int srow = tid >> 2;
    const int soff = (tid & 3) * 16;

    for (int j0 = 0; j0 < jend; j0 += 64) {
        *(ushort8*)&Ks[srow][soff]     = *(const ushort8*)&K[(size_t)(j0 + srow) * HD + soff];
        *(ushort8*)&Ks[srow][soff + 8] = *(const ushort8*)&K[(size_t)(j0 + srow) * HD + soff + 8];
        *(ushort8*)&Vs[srow][soff]     = *(const ushort8*)&V[(size_t)srow * SS + j0 + soff];
        *(ushort8*)&Vs[srow][soff + 8] = *(const ushort8*)&V[(size_t)srow * SS + j0 + soff + 8];
        __syncthreads();

        if (j0 <= wq_max) {
            floatx4 sf[2][4];
#pragma unroll
            for (int kg = 0; kg < 4; kg++) {
                bf16x8 kb0 = *(const bf16x8*)&Ks[kg * 16 + l15][quad * 8];
                bf16x8 kb1 = *(const bf16x8*)&Ks[kg * 16 + l15][32 + quad * 8];
#pragma unroll
                for (int m = 0; m < 2; m++) {
                    floatx4 s = zz;
                    s = __builtin_amdgcn_mfma_f32_16x16x32_bf16(qa[m][0], kb0, s, 0, 0, 0);
                    s = __builtin_amdgcn_mfma_f32_16x16x32_bf16(qa[m][1], kb1, s, 0, 0, 0);
                    sf[m][kg] = s;
                }
            }

            float alpha_[2][4];
#pragma unroll
            for (int m = 0; m < 2; m++)
#pragma unroll
                for (int i = 0; i < 4; i++) {
                    const int qrow = wrow0 + m * 16 + quad * 4 + i;
                    float pv4[4];
#pragma unroll
                    for (int kg = 0; kg < 4; kg++) {
                        const int key = j0 + kg * 16 + l15;
                        float s = sf[m][kg][i] * 0.125f;
                        if (key > qrow) s = -10000.0f;
                        pv4[kg] = s;
                    }
                    float t = fmaxf(fmaxf(pv4[0], pv4[1]), fmaxf(pv4[2], pv4[3]));
                    t = fmaxf(t, __shfl_xor(t, 1));
                    t = fmaxf(t, __shfl_xor(t, 2));
                    t = fmaxf(t, __shfl_xor(t, 4));
                    t = fmaxf(t, __shfl_xor(t, 8));
                    const float mnew = fmaxf(mrow[m][i], t);
                    const float al = __expf(mrow[m][i] - mnew);
                    mrow[m][i] = mnew;
                    float rs = 0.f;
#pragma unroll
                    for (int kg = 0; kg < 4; kg++) {
                        const float p = __expf(pv4[kg] - mnew);
                        Pl[w][m * 16 + quad * 4 + i][kg * 16 + l15] = f2bf(p);
                        rs += p;
                    }
                    rs += __shfl_xor(rs, 1);
                    rs += __shfl_xor(rs, 2);
                    rs += __shfl_xor(rs, 4);
                    rs += __shfl_xor(rs, 8);
                    lrow[m][i] = lrow[m][i] * al + rs;
                    alpha_[m][i] = al;
                }

#pragma unroll
            for (int m = 0; m < 2; m++)
#pragma unroll
                for (int nf = 0; nf < 4; nf++)
#pragma unroll
                    for (int i = 0; i < 4; i++) o[m][nf][i] *= alpha_[m][i];

            bf16x8 pa[2][2];
#pragma unroll
            for (int m = 0; m < 2; m++) {
                pa[m][0] = *(const bf16x8*)&Pl[w][m * 16 + l15][quad * 8];
                pa[m][1] = *(const bf16x8*)&Pl[w][m * 16 + l15][32 + quad * 8];
            }

#pragma unroll
            for (int nf = 0; nf < 4; nf++) {
                bf16x8 vb0 = *(const bf16x8*)&Vs[nf * 16 + l15][quad * 8];
                bf16x8 vb1 = *(const bf16x8*)&Vs[nf * 16 + l15][32 + quad * 8];
#pragma unroll
                for (int m = 0; m < 2; m++) {
                    o[m][nf] = __builtin_amdgcn_mfma_f32_16x16x32_bf16(pa[m][0], vb0, o[m][nf], 0, 0, 0);
                    o[m][nf] = __builtin_amdgcn_mfma_f32_16x16x32_bf16(pa[m][1], vb1, o[m][nf], 0, 0, 0);
                }
            }
        }
        __syncthreads();
    }

#pragma unroll
    for (int m = 0; m < 2; m++)
#pragma unroll
        for (int nf = 0; nf < 4; nf++)
#pragma unroll
            for (int i = 0; i < 4; i++) {
                const int s = wrow0 + m * 16 + quad * 4 + i;
                amerged[(size_t)(b * SS + s) * NXX + h * HD + nf * 16 + l15] =
                    f2bf(o[m][nf][i] / lrow[m][i]);
            }
}

extern "C" void kernel_launch(void* const* d_in, const int* in_sizes, int n_in,
                              void* d_out, int out_size, void* d_ws, size_t ws_size,
                              hipStream_t stream) {
    const void* x     = d_in[0];
    const void* Wqkv  = d_in[1];
    const void* bqkv  = d_in[2];
    const void* Wproj = d_in[3];
    const void* bproj = d_in[4];

    int* flag = (int*)d_ws;
    unsigned short* ws = (unsigned short*)d_ws + 8;
    unsigned short* WqkvT   = ws;                        // 3072*1024  (6 MB)
    unsigned short* WprojT  = WqkvT + 3072 * 1024;       // 1024*1024  (2 MB)
    unsigned short* q_ws    = WprojT + 1024 * 1024;      // 8M         (16 MB)
    unsigned short* kbf     = q_ws + 8 * 1024 * 1024;    // 8M         (16 MB)
    unsigned short* vbfT    = kbf + 8 * 1024 * 1024;     // 8M         (16 MB)
    unsigned short* amerged = vbfT + 8 * 1024 * 1024;    // 8M         (16 MB)
    unsigned short* xbf     = amerged;                   // ALIAS: xbf dead before attn writes amerged
    // total ws: ~72 MB

    sniff_k<<<1, 64, 0, stream>>>((const unsigned short*)x, flag);
    convert_x<<<dim3(8 * 1024 * 1024 / (256 * 8)), 256, 0, stream>>>(x, xbf, flag);
    transpose_k<<<dim3(3072 / 32, 1024 / 32), 256, 0, stream>>>(Wqkv, WqkvT, 1024, 3072, flag);
    transpose_k<<<dim3(1024 / 32, 1024 / 32), 256, 0, stream>>>(Wproj, WprojT, 1024, 1024, flag);
    gemm_bt<1><<<dim3(3072 / 128, 8192 / 128), 256, 0, stream>>>(
        xbf, WqkvT, bqkv, d_out, q_ws, kbf, vbfT, 8192, 3072, 1024, flag);
    attn<<<dim3(BB * NH * (SS / 128)), 256, 0, stream>>>(q_ws, kbf, vbfT, amerged);
    gemm_bt<0><<<dim3(1024 / 128, 8192 / 128), 256, 0, stream>>>(
        amerged, WprojT, bproj, d_out, nullptr, nullptr, nullptr, 8192, 1024, 1024, flag);
}

// Round 6
// 387.096 us; speedup vs baseline: 1.5234x; 1.1741x over previous
//
#include <hip/hip_runtime.h>
#include <stdint.h>

// Problem: B=8, S=1024, NX=1024, H=16, D=64 (GPT-2 attention block)
// out = [ a: B*S*NX ][ present_k: B*H*S*D ][ present_v: B*H*S*D ]
// Input/output dtype sniffed at runtime (fp32 vs bf16); internals bf16.

#define BB 8
#define SS 1024
#define NXX 1024
#define NH 16
#define HD 64

typedef __bf16 bf16x8 __attribute__((ext_vector_type(8)));
typedef float  floatx4 __attribute__((ext_vector_type(4)));
typedef unsigned short ushort8 __attribute__((ext_vector_type(8)));
typedef unsigned short ushortx4 __attribute__((ext_vector_type(4)));  // NB: 'ushort4' collides with HIP builtin

__device__ inline float bf2f(unsigned short u) {
    unsigned int x = ((unsigned int)u) << 16;
    float f;
    __builtin_memcpy(&f, &x, 4);
    return f;
}
__device__ inline unsigned short f2bf(float f) {
    unsigned int u;
    __builtin_memcpy(&u, &f, 4);
    u += 0x7FFFu + ((u >> 16) & 1u);  // RNE
    return (unsigned short)(u >> 16);
}

// async global->LDS, 16B per lane (dest = wave-uniform base + lane*16)
__device__ inline void gload_lds16(const unsigned short* g, unsigned short* l) {
    __builtin_amdgcn_global_load_lds(
        (const __attribute__((address_space(1))) void*)g,
        (__attribute__((address_space(3))) void*)l, 16, 0, 0);
}

// ---------------- dtype sniff: flag=1 if data is fp32, 0 if bf16 ----------------
__global__ void sniff_k(const unsigned short* __restrict__ x, int* __restrict__ flag) {
    if (threadIdx.x == 0 && blockIdx.x == 0) {
        int g = 0;
        for (int i = 0; i < 512; i++) {
            float f = bf2f(x[i]);
            float a = fabsf(f);
            if (!(a <= 1e4f)) g++;
            else if (f != 0.f && a < 1e-35f) g++;
        }
        *flag = (g > 16) ? 1 : 0;
    }
}

// ---------------- convert x -> bf16 (8 elems/thread) ----------------
__global__ __launch_bounds__(256) void convert_x(
    const void* __restrict__ in, unsigned short* __restrict__ out,
    const int* __restrict__ flagp) {
    const int f32 = *flagp;
    const size_t i = ((size_t)blockIdx.x * 256 + threadIdx.x) * 8;
    if (f32) {
        const floatx4* p = (const floatx4*)((const float*)in + i);
        floatx4 f0 = p[0], f1 = p[1];
        ushort8 u;
#pragma unroll
        for (int j = 0; j < 4; j++) { u[j] = f2bf(f0[j]); u[4 + j] = f2bf(f1[j]); }
        *(ushort8*)(out + i) = u;
    } else {
        *(ushort8*)(out + i) = *(const ushort8*)((const unsigned short*)in + i);
    }
}

// ---------------- transpose+convert: out_bf16[C][R] = in[R][C] ----------------
__global__ __launch_bounds__(256) void transpose_k(
    const void* __restrict__ in, unsigned short* __restrict__ out,
    int R, int C, const int* __restrict__ flagp) {
    const int f32 = *flagp;
    __shared__ unsigned short tile[32][33];
    int c0 = blockIdx.x * 32, r0 = blockIdx.y * 32;
    int tx = threadIdx.x & 31, ty = threadIdx.x >> 5;  // 32 x 8
    if (f32) {
        const float* inf = (const float*)in;
#pragma unroll
        for (int i = ty; i < 32; i += 8)
            tile[i][tx] = f2bf(inf[(r0 + i) * C + c0 + tx]);
    } else {
        const unsigned short* inu = (const unsigned short*)in;
#pragma unroll
        for (int i = ty; i < 32; i += 8)
            tile[i][tx] = inu[(r0 + i) * C + c0 + tx];
    }
    __syncthreads();
#pragma unroll
    for (int i = ty; i < 32; i += 8)
        out[(c0 + i) * R + r0 + tx] = tile[tx][i];
}

// ---------------- GEMM: C[M,N] = A[M,K] @ Bt[N,K]^T + bias[N] ----------------
// A, Bt: bf16. Staging via global_load_lds (16B/lane, m97 structure).
// MODE 0: writes `a` region of d_out in flag dtype.
// MODE 1: QKV scatter: q -> q_ws (bf16 [bh][s][d]); k -> d_out + kbf (bf16);
//         v -> d_out + vbfT (bf16 [bh][d][s], key-PERMUTED within 64-blocks:
//         store pos = (s&~63) | ((s&15)*4 + ((s>>4)&3)) ).
template <int MODE>
__global__ __launch_bounds__(256) void gemm_bt(
    const unsigned short* __restrict__ A,
    const unsigned short* __restrict__ Bt,
    const void* __restrict__ bias,
    void* __restrict__ outbase,
    unsigned short* __restrict__ q_ws,
    unsigned short* __restrict__ kbf,
    unsigned short* __restrict__ vbfT,
    int M, int N, int K, const int* __restrict__ flagp) {
    __shared__ __align__(16) unsigned short As[128 * 32];
    __shared__ __align__(16) unsigned short Bs[128 * 32];

    const int f32 = *flagp;
    const int tid  = threadIdx.x;
    const int lane = tid & 63;
    const int wave = tid >> 6;
    const int wr = wave >> 1, wc = wave & 1;
    const int l15 = lane & 15;
    const int quad = lane >> 4;
    const int row0 = blockIdx.y * 128;
    const int col0 = blockIdx.x * 128;

    floatx4 acc[4][4];
    floatx4 zz = {0.f, 0.f, 0.f, 0.f};
#pragma unroll
    for (int i = 0; i < 4; i++)
#pragma unroll
        for (int j = 0; j < 4; j++) acc[i][j] = zz;

    const int lrow = lane >> 2;
    const int lcol = (lane & 3) * 8;
    const unsigned short* Ag = A  + (size_t)(row0 + wave * 32 + lrow) * K + lcol;
    const unsigned short* Bg = Bt + (size_t)(col0 + wave * 32 + lrow) * K + lcol;
    unsigned short* Asl0 = &As[(wave * 32) * 32];
    unsigned short* Asl1 = &As[(wave * 32 + 16) * 32];
    unsigned short* Bsl0 = &Bs[(wave * 32) * 32];
    unsigned short* Bsl1 = &Bs[(wave * 32 + 16) * 32];

    for (int k0 = 0; k0 < K; k0 += 32) {
        gload_lds16(Ag + k0, Asl0);
        gload_lds16(Ag + k0 + (size_t)16 * K, Asl1);
        gload_lds16(Bg + k0, Bsl0);
        gload_lds16(Bg + k0 + (size_t)16 * K, Bsl1);
        __syncthreads();

        bf16x8 af[4], bfr[4];
#pragma unroll
        for (int mi = 0; mi < 4; mi++)
            af[mi] = *(const bf16x8*)&As[(wr * 64 + mi * 16 + l15) * 32 + quad * 8];
#pragma unroll
        for (int ni = 0; ni < 4; ni++)
            bfr[ni] = *(const bf16x8*)&Bs[(wc * 64 + ni * 16 + l15) * 32 + quad * 8];
#pragma unroll
        for (int mi = 0; mi < 4; mi++)
#pragma unroll
            for (int ni = 0; ni < 4; ni++)
                acc[mi][ni] = __builtin_amdgcn_mfma_f32_16x16x32_bf16(af[mi], bfr[ni], acc[mi][ni], 0, 0, 0);
        __syncthreads();
    }

    const size_t esz = f32 ? 4 : 2;
    char* kbase = (char*)outbase + (size_t)(BB * SS * NXX) * esz;
    char* vbase = (char*)outbase + (size_t)(2 * BB * SS * NXX) * esz;

#pragma unroll
    for (int mi = 0; mi < 4; mi++) {
#pragma unroll
        for (int ni = 0; ni < 4; ni++) {
            const int colb = col0 + wc * 64 + ni * 16 + l15;
            const float bv = f32 ? ((const float*)bias)[colb] : bf2f(((const unsigned short*)bias)[colb]);
#pragma unroll
            for (int i = 0; i < 4; i++) {
                const int row = row0 + wr * 64 + mi * 16 + quad * 4 + i;
                const float val = acc[mi][ni][i] + bv;
                if (MODE == 0) {
                    const size_t idx = (size_t)row * N + colb;
                    if (f32) ((float*)outbase)[idx] = val;
                    else     ((unsigned short*)outbase)[idx] = f2bf(val);
                } else {
                    const int sec    = colb >> 10;
                    const int within = colb & 1023;
                    const int h = within >> 6;
                    const int d = within & 63;
                    const int b = row >> 10;
                    const int s = row & 1023;
                    const int bh = b * NH + h;
                    const size_t idx = (size_t)(bh * SS + s) * HD + d;
                    const unsigned short obf = f2bf(val);
                    if (sec == 0) {
                        q_ws[idx] = obf;
                    } else if (sec == 1) {
                        if (f32) ((float*)kbase)[idx] = val;
                        else     ((unsigned short*)kbase)[idx] = obf;
                        kbf[idx] = obf;
                    } else {
                        if (f32) ((float*)vbase)[idx] = val;
                        else     ((unsigned short*)vbase)[idx] = obf;
                        const int s64 = s & 63;
                        const int sperm = (s & ~63) | ((s64 & 15) * 4 + (s64 >> 4));
                        vbfT[(size_t)(bh * HD + d) * SS + sperm] = obf;
                    }
                }
            }
        }
    }
}

// ---------------- flash attention: 4 waves/block, 2 paired Q-tiles/block ----------
// q_ws/kbf: [bh][s][d] bf16; vbfT: [bh][d][s] bf16 (key-permuted); amerged bf16.
__global__ __launch_bounds__(256) void attn(
    const unsigned short* __restrict__ q_ws,
    const unsigned short* __restrict__ kbf,
    const unsigned short* __restrict__ vbfT,
    unsigned short* __restrict__ amerged) {
    const int tid = threadIdx.x;
    const int lane = tid & 63;
    const int w = tid >> 6;
    const int l15 = lane & 15, quad = lane >> 4;
    const int blk = blockIdx.x;
    const int p = blk & 3;               // tile pair: {p, 7-p} (balanced: 18 units each)
    const int bh = blk >> 2;
    const int b = bh >> 4, h = bh & 15;

    const unsigned short* Q = q_ws + (size_t)bh * (SS * HD);
    const unsigned short* K = kbf + (size_t)bh * (SS * HD);
    const unsigned short* V = vbfT + (size_t)bh * (HD * SS);

    __shared__ __align__(16) unsigned short Ks[64][72];
    __shared__ __align__(16) unsigned short Vs[64][72];
    __shared__ __align__(16) unsigned short Pl[4][32][72];

    floatx4 zz = {0.f, 0.f, 0.f, 0.f};
    ushort8 ones_u;
#pragma unroll
    for (int j = 0; j < 8; j++) ones_u[j] = 0x3F80;  // bf16 1.0
    const bf16x8 ones = __builtin_bit_cast(bf16x8, ones_u);

    const int srow = tid >> 2;           // 0..63
    const int soff = (tid & 3) * 16;     // 0/16/32/48

#pragma unroll
    for (int tile = 0; tile < 2; tile++) {
        const int qb = tile ? (7 - p) : p;
        const int qbase = qb * 128;
        const int wrow0 = qbase + w * 32;
        const int wq_max = wrow0 + 31;
        const int jend = qbase + 128;

        bf16x8 qa[2][2];
#pragma unroll
        for (int m = 0; m < 2; m++)
#pragma unroll
            for (int t = 0; t < 2; t++)
                qa[m][t] = *(const bf16x8*)&Q[(size_t)(wrow0 + m * 16 + l15) * HD + t * 32 + quad * 8];

        floatx4 o[2][4], o5[2];
        float mrow[2][4];
#pragma unroll
        for (int m = 0; m < 2; m++) {
            o5[m] = zz;
#pragma unroll
            for (int i = 0; i < 4; i++) mrow[m][i] = -1e30f;
#pragma unroll
            for (int nf = 0; nf < 4; nf++) o[m][nf] = zz;
        }

        // prologue: stage chunk j0=0
        *(ushort8*)&Ks[srow][soff]     = *(const ushort8*)&K[(size_t)srow * HD + soff];
        *(ushort8*)&Ks[srow][soff + 8] = *(const ushort8*)&K[(size_t)srow * HD + soff + 8];
        *(ushort8*)&Vs[srow][soff]     = *(const ushort8*)&V[(size_t)srow * SS + soff];
        *(ushort8*)&Vs[srow][soff + 8] = *(const ushort8*)&V[(size_t)srow * SS + soff + 8];
        __syncthreads();

        for (int j0 = 0; j0 < jend; j0 += 64) {
            // ---- issue next chunk's global loads (overlap with compute) ----
            const bool havenext = (j0 + 64 < jend);
            ushort8 kn0, kn1, vn0, vn1;
            if (havenext) {
                kn0 = *(const ushort8*)&K[(size_t)(j0 + 64 + srow) * HD + soff];
                kn1 = *(const ushort8*)&K[(size_t)(j0 + 64 + srow) * HD + soff + 8];
                vn0 = *(const ushort8*)&V[(size_t)srow * SS + j0 + 64 + soff];
                vn1 = *(const ushort8*)&V[(size_t)srow * SS + j0 + 64 + soff + 8];
            }

            if (j0 <= wq_max) {
                // ---- scores over 64 keys ----
                floatx4 sf[2][4];
#pragma unroll
                for (int kg = 0; kg < 4; kg++) {
                    bf16x8 kb0 = *(const bf16x8*)&Ks[kg * 16 + l15][quad * 8];
                    bf16x8 kb1 = *(const bf16x8*)&Ks[kg * 16 + l15][32 + quad * 8];
#pragma unroll
                    for (int m = 0; m < 2; m++) {
                        floatx4 s = zz;
                        s = __builtin_amdgcn_mfma_f32_16x16x32_bf16(qa[m][0], kb0, s, 0, 0, 0);
                        s = __builtin_amdgcn_mfma_f32_16x16x32_bf16(qa[m][1], kb1, s, 0, 0, 0);
                        sf[m][kg] = s;
                    }
                }

                // ---- online softmax; P written permuted+packed (pos = l15*4+kg) ----
                float alpha_[2][4];
#pragma unroll
                for (int m = 0; m < 2; m++)
#pragma unroll
                    for (int i = 0; i < 4; i++) {
                        const int qrow = wrow0 + m * 16 + quad * 4 + i;
                        float pv4[4];
#pragma unroll
                        for (int kg = 0; kg < 4; kg++) {
                            const int key = j0 + kg * 16 + l15;
                            float s = sf[m][kg][i] * 0.125f;
                            if (key > qrow) s = -10000.0f;
                            pv4[kg] = s;
                        }
                        float t = fmaxf(fmaxf(pv4[0], pv4[1]), fmaxf(pv4[2], pv4[3]));
                        t = fmaxf(t, __shfl_xor(t, 1));
                        t = fmaxf(t, __shfl_xor(t, 2));
                        t = fmaxf(t, __shfl_xor(t, 4));
                        t = fmaxf(t, __shfl_xor(t, 8));
                        const float mnew = fmaxf(mrow[m][i], t);
                        alpha_[m][i] = __expf(mrow[m][i] - mnew);
                        mrow[m][i] = mnew;
                        ushortx4 pk;
#pragma unroll
                        for (int kg = 0; kg < 4; kg++)
                            pk[kg] = f2bf(__expf(pv4[kg] - mnew));
                        *(ushortx4*)&Pl[w][m * 16 + quad * 4 + i][l15 * 4] = pk;
                    }

                // ---- rescale o and o5 (running row-sum) ----
#pragma unroll
                for (int m = 0; m < 2; m++) {
#pragma unroll
                    for (int i = 0; i < 4; i++) o5[m][i] *= alpha_[m][i];
#pragma unroll
                    for (int nf = 0; nf < 4; nf++)
#pragma unroll
                        for (int i = 0; i < 4; i++) o[m][nf][i] *= alpha_[m][i];
                }

                // ---- P A-frags (wave-private LDS round trip) ----
                bf16x8 pa[2][2];
#pragma unroll
                for (int m = 0; m < 2; m++) {
                    pa[m][0] = *(const bf16x8*)&Pl[w][m * 16 + l15][quad * 8];
                    pa[m][1] = *(const bf16x8*)&Pl[w][m * 16 + l15][32 + quad * 8];
                }

                // ---- l via ones-MFMA; PV ----
#pragma unroll
                for (int m = 0; m < 2; m++) {
                    o5[m] = __builtin_amdgcn_mfma_f32_16x16x32_bf16(pa[m][0], ones, o5[m], 0, 0, 0);
                    o5[m] = __builtin_amdgcn_mfma_f32_16x16x32_bf16(pa[m][1], ones, o5[m], 0, 0, 0);
                }
#pragma unroll
                for (int nf = 0; nf < 4; nf++) {
                    bf16x8 vb0 = *(const bf16x8*)&Vs[nf * 16 + l15][quad * 8];
                    bf16x8 vb1 = *(const bf16x8*)&Vs[nf * 16 + l15][32 + quad * 8];
#pragma unroll
                    for (int m = 0; m < 2; m++) {
                        o[m][nf] = __builtin_amdgcn_mfma_f32_16x16x32_bf16(pa[m][0], vb0, o[m][nf], 0, 0, 0);
                        o[m][nf] = __builtin_amdgcn_mfma_f32_16x16x32_bf16(pa[m][1], vb1, o[m][nf], 0, 0, 0);
                    }
                }
            }
            __syncthreads();
            if (havenext) {
                *(ushort8*)&Ks[srow][soff]     = kn0;
                *(ushort8*)&Ks[srow][soff + 8] = kn1;
                *(ushort8*)&Vs[srow][soff]     = vn0;
                *(ushort8*)&Vs[srow][soff + 8] = vn1;
            }
            __syncthreads();
        }

        // ---- epilogue: l sits replicated in o5[m][i] across l15 lanes ----
#pragma unroll
        for (int m = 0; m < 2; m++)
#pragma unroll
            for (int nf = 0; nf < 4; nf++)
#pragma unroll
                for (int i = 0; i < 4; i++) {
                    const int s = wrow0 + m * 16 + quad * 4 + i;
                    amerged[(size_t)(b * SS + s) * NXX + h * HD + nf * 16 + l15] =
                        f2bf(o[m][nf][i] / o5[m][i]);
                }
        __syncthreads();  // protect Ks/Vs before next tile's prologue
    }
}

extern "C" void kernel_launch(void* const* d_in, const int* in_sizes, int n_in,
                              void* d_out, int out_size, void* d_ws, size_t ws_size,
                              hipStream_t stream) {
    const void* x     = d_in[0];
    const void* Wqkv  = d_in[1];
    const void* bqkv  = d_in[2];
    const void* Wproj = d_in[3];
    const void* bproj = d_in[4];

    int* flag = (int*)d_ws;
    unsigned short* ws = (unsigned short*)d_ws + 8;
    unsigned short* WqkvT   = ws;                        // 3072*1024  (6 MB)
    unsigned short* WprojT  = WqkvT + 3072 * 1024;       // 1024*1024  (2 MB)
    unsigned short* q_ws    = WprojT + 1024 * 1024;      // 8M         (16 MB)
    unsigned short* kbf     = q_ws + 8 * 1024 * 1024;    // 8M         (16 MB)
    unsigned short* vbfT    = kbf + 8 * 1024 * 1024;     // 8M         (16 MB)
    unsigned short* amerged = vbfT + 8 * 1024 * 1024;    // 8M         (16 MB)
    unsigned short* xbf     = amerged;                   // ALIAS: xbf dead before attn writes amerged
    // total ws: ~72 MB

    sniff_k<<<1, 64, 0, stream>>>((const unsigned short*)x, flag);
    convert_x<<<dim3(8 * 1024 * 1024 / (256 * 8)), 256, 0, stream>>>(x, xbf, flag);
    transpose_k<<<dim3(3072 / 32, 1024 / 32), 256, 0, stream>>>(Wqkv, WqkvT, 1024, 3072, flag);
    transpose_k<<<dim3(1024 / 32, 1024 / 32), 256, 0, stream>>>(Wproj, WprojT, 1024, 1024, flag);
    gemm_bt<1><<<dim3(3072 / 128, 8192 / 128), 256, 0, stream>>>(
        xbf, WqkvT, bqkv, d_out, q_ws, kbf, vbfT, 8192, 3072, 1024, flag);
    attn<<<dim3(BB * NH * 4), 256, 0, stream>>>(q_ws, kbf, vbfT, amerged);
    gemm_bt<0><<<dim3(1024 / 128, 8192 / 128), 256, 0, stream>>>(
        amerged, WprojT, bproj, d_out, nullptr, nullptr, nullptr, 8192, 1024, 1024, flag);
}